// Round 10
// baseline (287.879 us; speedup 1.0000x reference)
//
#include <hip/hip_runtime.h>
#include <float.h>
#include <math.h>

// Problem constants (S=4096 tokens, E=64 experts, CAP=128)
#define SS 4096
#define EE 64
#define CAPC 128
#define ROW 8192                  // E*CAP floats per token per tensor
#define SEC (4096LL * 64 * 128)   // elements per [S,E,C] tensor
#define NGATE 256                 // gate blocks (16 tokens each)
#define NFILL 4096                // fill blocks (16384 floats = 64 KB each)
#define TPB_TOK 16                // tokens per gate block

// native clang vector type — __builtin_nontemporal_store rejects HIP's
// float4 class wrapper but accepts this.
typedef float vfloat4 __attribute__((ext_vector_type(4)));

// ---------------------------------------------------------------------------
// K1: fused gate + fill (round-6 structure, known good).
//   blocks [0, 256):    gate for 16 tokens (4 waves x 4 tokens), local ranks,
//                       per-block expert counts / gate sums -> ws only.
//   blocks [256, 4352): pure fill — zero a contiguous 64 KB slice of out
//                       with NONTEMPORAL stores (lines are never re-read;
//                       keep them out of L2).
// Gate work (~5us) hides under the fill (~41us).
// ---------------------------------------------------------------------------
__global__ __launch_bounds__(256) void k1_gate_fill(
    const float* __restrict__ logits,
    const float* __restrict__ noise,
    int*   __restrict__ bc1,      // [256][64] per-block top1 counts
    int*   __restrict__ bc2,      // [256][64] per-block top2 counts
    float* __restrict__ pg,       // [256][64] per-block gate sums
    int*   __restrict__ tokmeta,  // [4096] packed idx/ranks
    float2* __restrict__ tokg,    // [4096] raw g1,g2
    float* __restrict__ out)
{
    const int tid = threadIdx.x;

    if (blockIdx.x >= NGATE) {
        // ---- pure fill block: zero floats [fb*16384, (fb+1)*16384) ----
        const int fb = blockIdx.x - NGATE;
        vfloat4* p = (vfloat4*)out + (long)fb * 4096;
        const vfloat4 z = {0.f, 0.f, 0.f, 0.f};
        #pragma unroll
        for (int i = 0; i < 16; ++i)
            __builtin_nontemporal_store(z, &p[i * 256 + tid]);
        if (fb == NFILL - 1 && tid == 0) out[2 * SEC] = 0.f;  // last element
        return;
    }

    // ---- gate block: 4 waves, each handles 4 tokens ----
    const int b    = blockIdx.x;
    const int wave = tid >> 6;
    const int lane = tid & 63;

    __shared__ int   s_idx1[TPB_TOK], s_idx2[TPB_TOK];
    __shared__ float s_gate[TPB_TOK][64];

    #pragma unroll
    for (int t4 = 0; t4 < 4; ++t4) {
        const int t = wave * 4 + t4;        // token within block
        const int s = b * TPB_TOK + t;
        const float l = logits[s * EE + lane];
        const float n = noise [s * EE + lane];

        // argmax over logits, first-index tie-break (all lanes agree)
        float v = l; int bi = lane;
        #pragma unroll
        for (int off = 32; off; off >>= 1) {
            float v2 = __shfl_xor(v, off, 64);
            int   i2 = __shfl_xor(bi, off, 64);
            if (v2 > v || (v2 == v && i2 < bi)) { v = v2; bi = i2; }
        }
        const int idx1 = bi;

        float e = expf(l - v);
        float sum = e;
        #pragma unroll
        for (int off = 32; off; off >>= 1) sum += __shfl_xor(sum, off, 64);
        const float gate = e / sum;

        // top-2 from logits+noise with top-1 masked to -FLT_MAX
        float lw = (lane == idx1) ? -FLT_MAX : (l + n);
        float v2v = lw; int bi2 = lane;
        #pragma unroll
        for (int off = 32; off; off >>= 1) {
            float q  = __shfl_xor(v2v, off, 64);
            int   i2 = __shfl_xor(bi2, off, 64);
            if (q > v2v || (q == v2v && i2 < bi2)) { v2v = q; bi2 = i2; }
        }
        const int idx2 = bi2;

        s_gate[t][lane] = gate;
        const float g1v = __shfl(gate, idx1, 64);
        const float g2v = __shfl(gate, idx2, 64);
        if (lane == 0) {
            s_idx1[t] = idx1;
            s_idx2[t] = idx2;
            tokg[s] = make_float2(g1v, g2v);
        }
    }
    __syncthreads();

    // ---- per-block expert counts + gate sums, local ranks ----
    if (tid < 64) {
        int c1 = 0, c2 = 0;
        float gs = 0.f;
        #pragma unroll
        for (int j = 0; j < TPB_TOK; ++j) {
            c1 += (s_idx1[j] == tid);
            c2 += (s_idx2[j] == tid);
            gs += s_gate[j][tid];
        }
        bc1[b * 64 + tid] = c1;
        bc2[b * 64 + tid] = c2;
        pg [b * 64 + tid] = gs;
    } else if (tid < 64 + TPB_TOK) {
        const int t = tid - 64;
        const int m1 = s_idx1[t], m2 = s_idx2[t];
        int r1 = 0, r2 = 0;
        for (int j = 0; j < t; ++j) {
            r1 += (s_idx1[j] == m1);
            r2 += (s_idx2[j] == m2);
        }
        tokmeta[b * TPB_TOK + t] = m1 | (m2 << 6) | (r1 << 12) | (r2 << 17);
    }
}

// ---------------------------------------------------------------------------
// K2: redundant per-block prefix scan (bc arrays are L2-resident) + scatter
// of this block's 16 tokens. Block 0 also computes l_aux.
// 256 blocks x 256 threads. Stream order guarantees out is fully zeroed.
// ---------------------------------------------------------------------------
__global__ __launch_bounds__(256) void k2_scan_scatter(
    const int*   __restrict__ bc1,
    const int*   __restrict__ bc2,
    const float* __restrict__ pg,
    const int*   __restrict__ tokmeta,
    const float2* __restrict__ tokg,
    float* __restrict__ out)
{
    const int tid = threadIdx.x;
    const int b   = blockIdx.x;

    __shared__ int   s_off1[64], s_off2[64], s_cnt1[64];
    __shared__ float s_gs[64];

    if (tid < 64) {
        // exclusive prefix of bc1 over blocks, capture own offset + total
        int o1 = 0, mine = 0;
        #pragma unroll 8
        for (int blk = 0; blk < NGATE; ++blk) {
            if (blk == b) mine = o1;
            o1 += bc1[blk * 64 + tid];
        }
        s_off1[tid] = mine;
        s_cnt1[tid] = o1;
    } else if (tid < 128) {
        const int e = tid - 64;
        int o2 = 0, mine = 0;
        #pragma unroll 8
        for (int blk = 0; blk < NGATE; ++blk) {
            if (blk == b) mine = o2;
            o2 += bc2[blk * 64 + e];
        }
        s_off2[e] = mine;
    } else if (tid < 192 && b == 0) {
        const int e = tid - 128;
        float gs = 0.f;
        #pragma unroll 8
        for (int blk = 0; blk < NGATE; ++blk) gs += pg[blk * 64 + e];
        s_gs[e] = gs;
    }
    __syncthreads();

    if (tid < TPB_TOK) {
        const int s = b * TPB_TOK + tid;
        const int m = tokmeta[s];
        const int i1  =  m        & 63;
        const int i2  = (m >> 6)  & 63;
        const int lr1 = (m >> 12) & 31;
        const int lr2 = (m >> 17) & 31;
        const float2 g = tokg[s];
        const int loc1 = lr1 + s_off1[i1];
        const int loc2 = lr2 + s_off2[i2] + s_cnt1[i2];
        float g1 = g.x, g2 = g.y;
        const bool k1 = loc1 < CAPC, k2 = loc2 < CAPC;
        g1 = k1 ? g1 : 0.f;
        g2 = k2 ? g2 : 0.f;
        const float denom = fmaxf(g1 + g2, 1.1920929e-07f);  // finfo(f32).eps
        g1 /= denom;
        g2 /= denom;
        float* combine = out + 1;
        float* mask    = out + 1 + SEC;
        const long base = (long)s * ROW;
        if (k1 && g1 != 0.f) {
            const long p = base + (long)i1 * CAPC + loc1;
            combine[p] = g1;
            mask[p]    = 1.f;
        }
        if (k2 && g2 != 0.f) {
            const long p = base + (long)i2 * CAPC + loc2;
            combine[p] = g2;
            mask[p]    = 1.f;
        }
    } else if (tid == 64 + TPB_TOK && b == 0) {
        // l_aux = (E / S^2) * sum_e gs_e * cnt1_e
        float prod = 0.f;
        #pragma unroll 8
        for (int e = 0; e < 64; ++e) prod += s_gs[e] * (float)s_cnt1[e];
        out[0] = prod * (float)EE / ((float)SS * (float)SS);
    }
}

// ---------------------------------------------------------------------------
// Launch: fused gate+fill -> scan+scatter.
// ---------------------------------------------------------------------------
extern "C" void kernel_launch(void* const* d_in, const int* in_sizes, int n_in,
                              void* d_out, int out_size, void* d_ws, size_t ws_size,
                              hipStream_t stream) {
    const float* logits = (const float*)d_in[0];
    const float* noise  = (const float*)d_in[1];
    float* out = (float*)d_out;

    char* ws = (char*)d_ws;
    int*    bc1     = (int*)   (ws + 0);        // 64 KB
    int*    bc2     = (int*)   (ws + 65536);    // 64 KB
    float*  pg      = (float*) (ws + 131072);   // 64 KB
    int*    tokmeta = (int*)   (ws + 196608);   // 16 KB
    float2* tokg    = (float2*)(ws + 212992);   // 32 KB

    k1_gate_fill<<<NGATE + NFILL, 256, 0, stream>>>(logits, noise, bc1, bc2, pg,
                                                    tokmeta, tokg, out);
    k2_scan_scatter<<<NGATE, 256, 0, stream>>>(bc1, bc2, pg, tokmeta, tokg, out);
}

// Round 11
// 274.166 us; speedup vs baseline: 1.0500x; 1.0500x over previous
//
#include <hip/hip_runtime.h>
#include <float.h>
#include <math.h>

// Problem constants (S=4096 tokens, E=64 experts, CAP=128)
#define SS 4096
#define EE 64
#define CAPC 128
#define ROW 8192                  // E*CAP floats per token per tensor
#define SEC (4096LL * 64 * 128)   // elements per [S,E,C] tensor
#define NGATE 256                 // gate blocks (16 tokens each)
#define NFILL 4096                // fill blocks (16384 floats = 64 KB each)
#define TPB_TOK 16                // tokens per gate block

// ---------------------------------------------------------------------------
// K1: fused gate + fill (round-6 structure, measured best: 274.4 us total).
//   blocks [0, 256):    gate for 16 tokens (4 waves x 4 tokens), local ranks,
//                       per-block expert counts / gate sums -> ws only.
//   blocks [256, 4352): pure fill — zero a contiguous 64 KB slice of out.
// Gate work (~5us) hides under the fill (~41us). Regular float4 stores:
// nontemporal variant measured neutral-to-negative (round 10).
// ---------------------------------------------------------------------------
__global__ __launch_bounds__(256) void k1_gate_fill(
    const float* __restrict__ logits,
    const float* __restrict__ noise,
    int*   __restrict__ bc1,      // [256][64] per-block top1 counts
    int*   __restrict__ bc2,      // [256][64] per-block top2 counts
    float* __restrict__ pg,       // [256][64] per-block gate sums
    int*   __restrict__ tokmeta,  // [4096] packed idx/ranks
    float2* __restrict__ tokg,    // [4096] raw g1,g2
    float* __restrict__ out)
{
    const int tid = threadIdx.x;

    if (blockIdx.x >= NGATE) {
        // ---- pure fill block: zero floats [fb*16384, (fb+1)*16384) ----
        const int fb = blockIdx.x - NGATE;
        float4* p = (float4*)out + (long)fb * 4096;
        const float4 z = make_float4(0.f, 0.f, 0.f, 0.f);
        #pragma unroll
        for (int i = 0; i < 16; ++i) p[i * 256 + tid] = z;
        if (fb == NFILL - 1 && tid == 0) out[2 * SEC] = 0.f;  // last element
        return;
    }

    // ---- gate block: 4 waves, each handles 4 tokens ----
    const int b    = blockIdx.x;
    const int wave = tid >> 6;
    const int lane = tid & 63;

    __shared__ int   s_idx1[TPB_TOK], s_idx2[TPB_TOK];
    __shared__ float s_gate[TPB_TOK][64];

    #pragma unroll
    for (int t4 = 0; t4 < 4; ++t4) {
        const int t = wave * 4 + t4;        // token within block
        const int s = b * TPB_TOK + t;
        const float l = logits[s * EE + lane];
        const float n = noise [s * EE + lane];

        // argmax over logits, first-index tie-break (all lanes agree)
        float v = l; int bi = lane;
        #pragma unroll
        for (int off = 32; off; off >>= 1) {
            float v2 = __shfl_xor(v, off, 64);
            int   i2 = __shfl_xor(bi, off, 64);
            if (v2 > v || (v2 == v && i2 < bi)) { v = v2; bi = i2; }
        }
        const int idx1 = bi;

        float e = expf(l - v);
        float sum = e;
        #pragma unroll
        for (int off = 32; off; off >>= 1) sum += __shfl_xor(sum, off, 64);
        const float gate = e / sum;

        // top-2 from logits+noise with top-1 masked to -FLT_MAX
        float lw = (lane == idx1) ? -FLT_MAX : (l + n);
        float v2v = lw; int bi2 = lane;
        #pragma unroll
        for (int off = 32; off; off >>= 1) {
            float q  = __shfl_xor(v2v, off, 64);
            int   i2 = __shfl_xor(bi2, off, 64);
            if (q > v2v || (q == v2v && i2 < bi2)) { v2v = q; bi2 = i2; }
        }
        const int idx2 = bi2;

        s_gate[t][lane] = gate;
        const float g1v = __shfl(gate, idx1, 64);
        const float g2v = __shfl(gate, idx2, 64);
        if (lane == 0) {
            s_idx1[t] = idx1;
            s_idx2[t] = idx2;
            tokg[s] = make_float2(g1v, g2v);
        }
    }
    __syncthreads();

    // ---- per-block expert counts + gate sums, local ranks ----
    if (tid < 64) {
        int c1 = 0, c2 = 0;
        float gs = 0.f;
        #pragma unroll
        for (int j = 0; j < TPB_TOK; ++j) {
            c1 += (s_idx1[j] == tid);
            c2 += (s_idx2[j] == tid);
            gs += s_gate[j][tid];
        }
        bc1[b * 64 + tid] = c1;
        bc2[b * 64 + tid] = c2;
        pg [b * 64 + tid] = gs;
    } else if (tid < 64 + TPB_TOK) {
        const int t = tid - 64;
        const int m1 = s_idx1[t], m2 = s_idx2[t];
        int r1 = 0, r2 = 0;
        for (int j = 0; j < t; ++j) {
            r1 += (s_idx1[j] == m1);
            r2 += (s_idx2[j] == m2);
        }
        tokmeta[b * TPB_TOK + t] = m1 | (m2 << 6) | (r1 << 12) | (r2 << 17);
    }
}

// ---------------------------------------------------------------------------
// K2: redundant per-block prefix scan (bc arrays are L2-resident) + scatter
// of this block's 16 tokens. Block 0 also computes l_aux.
// 256 blocks x 256 threads. Stream order guarantees out is fully zeroed.
// ---------------------------------------------------------------------------
__global__ __launch_bounds__(256) void k2_scan_scatter(
    const int*   __restrict__ bc1,
    const int*   __restrict__ bc2,
    const float* __restrict__ pg,
    const int*   __restrict__ tokmeta,
    const float2* __restrict__ tokg,
    float* __restrict__ out)
{
    const int tid = threadIdx.x;
    const int b   = blockIdx.x;

    __shared__ int   s_off1[64], s_off2[64], s_cnt1[64];
    __shared__ float s_gs[64];

    if (tid < 64) {
        // exclusive prefix of bc1 over blocks, capture own offset + total
        int o1 = 0, mine = 0;
        #pragma unroll 8
        for (int blk = 0; blk < NGATE; ++blk) {
            if (blk == b) mine = o1;
            o1 += bc1[blk * 64 + tid];
        }
        s_off1[tid] = mine;
        s_cnt1[tid] = o1;
    } else if (tid < 128) {
        const int e = tid - 64;
        int o2 = 0, mine = 0;
        #pragma unroll 8
        for (int blk = 0; blk < NGATE; ++blk) {
            if (blk == b) mine = o2;
            o2 += bc2[blk * 64 + e];
        }
        s_off2[e] = mine;
    } else if (tid < 192 && b == 0) {
        const int e = tid - 128;
        float gs = 0.f;
        #pragma unroll 8
        for (int blk = 0; blk < NGATE; ++blk) gs += pg[blk * 64 + e];
        s_gs[e] = gs;
    }
    __syncthreads();

    if (tid < TPB_TOK) {
        const int s = b * TPB_TOK + tid;
        const int m = tokmeta[s];
        const int i1  =  m        & 63;
        const int i2  = (m >> 6)  & 63;
        const int lr1 = (m >> 12) & 31;
        const int lr2 = (m >> 17) & 31;
        const float2 g = tokg[s];
        const int loc1 = lr1 + s_off1[i1];
        const int loc2 = lr2 + s_off2[i2] + s_cnt1[i2];
        float g1 = g.x, g2 = g.y;
        const bool k1 = loc1 < CAPC, k2 = loc2 < CAPC;
        g1 = k1 ? g1 : 0.f;
        g2 = k2 ? g2 : 0.f;
        const float denom = fmaxf(g1 + g2, 1.1920929e-07f);  // finfo(f32).eps
        g1 /= denom;
        g2 /= denom;
        float* combine = out + 1;
        float* mask    = out + 1 + SEC;
        const long base = (long)s * ROW;
        if (k1 && g1 != 0.f) {
            const long p = base + (long)i1 * CAPC + loc1;
            combine[p] = g1;
            mask[p]    = 1.f;
        }
        if (k2 && g2 != 0.f) {
            const long p = base + (long)i2 * CAPC + loc2;
            combine[p] = g2;
            mask[p]    = 1.f;
        }
    } else if (tid == 64 + TPB_TOK && b == 0) {
        // l_aux = (E / S^2) * sum_e gs_e * cnt1_e
        float prod = 0.f;
        #pragma unroll 8
        for (int e = 0; e < 64; ++e) prod += s_gs[e] * (float)s_cnt1[e];
        out[0] = prod * (float)EE / ((float)SS * (float)SS);
    }
}

// ---------------------------------------------------------------------------
// Launch: fused gate+fill -> scan+scatter.
// ---------------------------------------------------------------------------
extern "C" void kernel_launch(void* const* d_in, const int* in_sizes, int n_in,
                              void* d_out, int out_size, void* d_ws, size_t ws_size,
                              hipStream_t stream) {
    const float* logits = (const float*)d_in[0];
    const float* noise  = (const float*)d_in[1];
    float* out = (float*)d_out;

    char* ws = (char*)d_ws;
    int*    bc1     = (int*)   (ws + 0);        // 64 KB
    int*    bc2     = (int*)   (ws + 65536);    // 64 KB
    float*  pg      = (float*) (ws + 131072);   // 64 KB
    int*    tokmeta = (int*)   (ws + 196608);   // 16 KB
    float2* tokg    = (float2*)(ws + 212992);   // 32 KB

    k1_gate_fill<<<NGATE + NFILL, 256, 0, stream>>>(logits, noise, bc1, bc2, pg,
                                                    tokmeta, tokg, out);
    k2_scan_scatter<<<NGATE, 256, 0, stream>>>(bc1, bc2, pg, tokmeta, tokg, out);
}